// Round 6
// baseline (527.271 us; speedup 1.0000x reference)
//
#include <hip/hip_runtime.h>
#include <hip/hip_bf16.h>
#include <math.h>

typedef unsigned int  uint;
typedef unsigned short ushort;
typedef unsigned long long u64;

// Problem constants
#define DD    256      // embedding dim
#define KK    2048     // num codewords
#define HW    1024     // H*W
#define NN    32768    // rows
#define NUMEL 8388608  // total elements
#define STRIDEB (DD*HW)
#define NBLK_QL (NUMEL/1024)   // 8192 quant_loss blocks

// Workspace layout (bytes) — total ~2.27 MB
#define WS_H2     0         // 2048 f32: 0.5*||e_k||^2
#define WS_COUNTS 8192      // 2048 i32
#define WS_EBF    16512     // emb frag-ordered bf16 hi/lo: 2 MB
#define WS_PACK   2113664   // 32768 u64 packed (mapped_score<<32 | idx)
#define WS_BPART  WS_PACK   // 8192 f32 (aliases pack; pack dead after merge)

// Output layout (floats): quantized_st | loss | perplexity | indices(as float)
#define OUT_LOSS  8388608
#define OUT_PPL   8388609
#define OUT_IDX   8388610

typedef __attribute__((ext_vector_type(8))) short  short8;   // 8 bf16 (4 VGPR)
typedef __attribute__((ext_vector_type(4))) float  float4v;  // 4 fp32 acc

__device__ __forceinline__ ushort f2bf(float f) {   // RNE fp32->bf16 bits
    uint u = __float_as_uint(f);
    return (ushort)((u + 0x7FFFu + ((u >> 16) & 1u)) >> 16);
}

// --------------------------------------------------------------------------
// Kernel 1: h2[k] = 0.5*sum_d emb[d][k]^2; zero histogram; init pack to MAX.
__global__ __launch_bounds__(256) void e2h_kernel(const float* __restrict__ emb,
                                                  float* __restrict__ h2,
                                                  int*   __restrict__ counts,
                                                  u64*   __restrict__ pack) {
    int k = blockIdx.x * 256 + threadIdx.x;
    float s = 0.f;
    for (int d = 0; d < DD; ++d) {
        float v = emb[(size_t)d * KK + k];
        s += v * v;
    }
    h2[k] = 0.5f * s;
    counts[k] = 0;
#pragma unroll
    for (int i = 0; i < 16; ++i) pack[k * 16 + i] = ~0ull;
}

// --------------------------------------------------------------------------
// Kernel 2: reorder emb (D,K) fp32 into MFMA-B-fragment-major bf16 hi/lo.
__global__ __launch_bounds__(256) void prep_emb(const float* __restrict__ emb,
                                                ushort* __restrict__ ebf) {
    int g  = blockIdx.x * 256 + threadIdx.x;
    int k  = g & (KK - 1);
    int dg = g >> 11;          // 0..31
    int d0 = dg * 8;
    int s    = dg >> 2;
    int quad = dg & 3;
    int ct   = k >> 4;
    int l    = quad * 16 + (k & 15);

    union { ushort us[8]; uint4 v; } hu, lu;
#pragma unroll
    for (int j = 0; j < 8; ++j) {
        float v = emb[(size_t)(d0 + j) * KK + k];
        ushort hb = f2bf(v);
        float  hf = __uint_as_float(((uint)hb) << 16);
        hu.us[j] = hb;
        lu.us[j] = f2bf(v - hf);
    }
    size_t hi_off = (size_t)(((ct * 8 + s) * 2 + 0) * 64 + l) * 8;
    size_t lo_off = (size_t)(((ct * 8 + s) * 2 + 1) * 64 + l) * 8;
    *(uint4*)(ebf + hi_off) = hu.v;
    *(uint4*)(ebf + lo_off) = lu.v;
}

// --------------------------------------------------------------------------
// Kernel 3: split-bf16 MFMA distance + per-row argmin over a 512-col chunk.
// R6: grid 1024 (256 row-blocks x 4 col-chunks) -> 4 blocks/CU, 4 waves/SIMD.
// (R5 post-mortem: at 2 blocks/CU the per-ct barrier kept all waves in
// lockstep -> MFMA/VALU/LDS phases serialized; MfmaUtil pinned at 36%.
// Independent co-resident blocks desynchronize the phases.)
// Result merging across chunks: atomicMin on packed u64
// (monotone(score)<<32 | idx) == min-value-then-min-index, jnp tie order.
__global__ __launch_bounds__(256, 4) void argmin_mfma(
    const float*  __restrict__ x,
    const ushort* __restrict__ ebf,
    const float*  __restrict__ h2,
    u64*  __restrict__ pack)
{
    __shared__ ushort sB[16384];  // 32 KB: two 16 KB B-tile buffers
    __shared__ float  sH[512];    // 2 KB: h2 slice for this col-chunk

    const int tid  = threadIdx.x;
    const int w    = tid >> 6;
    const int lane = tid & 63;
    const int m    = lane & 15;
    const int quad = lane >> 4;

    const int rb = blockIdx.x >> 2;
    const int ch = blockIdx.x & 3;
    const int n0 = rb * 128 + w * 32;          // wave's first row
    const int b  = n0 >> 10;
    const int hwb = n0 & 1023;
    const float* xb = x + (size_t)b * STRIDEB;
    const int cbase = ch * 512;
    const int ctg0  = cbase >> 4;

    // Async stage of one 16 KB B tile (ctg) into buffer bufsel.
    auto stage = [&](int bufsel, int ctg) {
        const char* gb = (const char*)ebf + (size_t)ctg * 16384;
        char* lb = (char*)sB + (bufsel << 14);
#pragma unroll
        for (int i = 0; i < 4; ++i) {
            const int chunk = (w * 4 + i) << 10;
            __builtin_amdgcn_global_load_lds(
                (const __attribute__((address_space(1))) uint*)(gb + chunk + lane * 16),
                (__attribute__((address_space(3))) uint*)(lb + chunk),
                16, 0, 0);
        }
    };

    // Prologue: h2 slice -> LDS (512 f32 = 128 lanes x 16 B)
    if (tid < 128) ((float4*)sH)[tid] = ((const float4*)(h2 + cbase))[tid];
    stage(0, ctg0);

    // A fragments in registers: 2 strips x 8 slices x (hi,lo) = 128 VGPRs.
    short8 xh[2][8], xl[2][8];
#pragma unroll
    for (int st = 0; st < 2; ++st) {
        const int hw = hwb + st * 16 + m;
#pragma unroll
        for (int s = 0; s < 8; ++s) {
            const float* p = xb + (size_t)(s * 32 + quad * 8) * HW + hw;
            short8 hh, ll;
#pragma unroll
            for (int j = 0; j < 8; ++j) {
                float v = p[(size_t)j * HW];
                v = fminf(fmaxf(v, -10.f), 10.f);
                ushort hb = f2bf(v);
                float  hf = __uint_as_float(((uint)hb) << 16);
                hh[j] = (short)hb;
                ll[j] = (short)f2bf(v - hf);
            }
            xh[st][s] = hh;
            xl[st][s] = ll;
        }
    }

    float bv[2][4] = {{1e30f,1e30f,1e30f,1e30f},{1e30f,1e30f,1e30f,1e30f}};
    int   bi[2][4] = {{0,0,0,0},{0,0,0,0}};

    for (int ct = 0; ct < 32; ++ct) {
        __syncthreads();   // drains prefetch of buf(ct&1); protects buf((ct+1)&1)
        if (ct < 31) stage((ct + 1) & 1, ctg0 + ct + 1);

        const ushort* bufc = sB + ((ct & 1) << 13);
        float4v ahh0 = {0,0,0,0}, ahl0 = {0,0,0,0}, alh0 = {0,0,0,0};
        float4v ahh1 = {0,0,0,0}, ahl1 = {0,0,0,0}, alh1 = {0,0,0,0};
#pragma unroll
        for (int s = 0; s < 8; ++s) {
            short8 eh = *(const short8*)&bufc[(s * 2 + 0) * 512 + lane * 8];
            short8 el = *(const short8*)&bufc[(s * 2 + 1) * 512 + lane * 8];
            alh0 = __builtin_amdgcn_mfma_f32_16x16x32_bf16(xl[0][s], eh, alh0, 0, 0, 0);
            ahl0 = __builtin_amdgcn_mfma_f32_16x16x32_bf16(xh[0][s], el, ahl0, 0, 0, 0);
            ahh0 = __builtin_amdgcn_mfma_f32_16x16x32_bf16(xh[0][s], eh, ahh0, 0, 0, 0);
            alh1 = __builtin_amdgcn_mfma_f32_16x16x32_bf16(xl[1][s], eh, alh1, 0, 0, 0);
            ahl1 = __builtin_amdgcn_mfma_f32_16x16x32_bf16(xh[1][s], el, ahl1, 0, 0, 0);
            ahh1 = __builtin_amdgcn_mfma_f32_16x16x32_bf16(xh[1][s], eh, ahh1, 0, 0, 0);
        }
        const int c  = cbase + ct * 16 + m;
        const float hv = sH[ct * 16 + m];
#pragma unroll
        for (int i = 0; i < 4; ++i) {
            float s0 = hv - (ahh0[i] + (ahl0[i] + alh0[i]));
            float s1 = hv - (ahh1[i] + (ahl1[i] + alh1[i]));
            if (s0 < bv[0][i]) { bv[0][i] = s0; bi[0][i] = c; }
            if (s1 < bv[1][i]) { bv[1][i] = s1; bi[1][i] = c; }
        }
    }

    // Reduce across the 16 lanes of each quad, then atomicMin-merge.
#pragma unroll
    for (int st = 0; st < 2; ++st) {
#pragma unroll
        for (int i = 0; i < 4; ++i) {
            float v  = bv[st][i];
            int   ix = bi[st][i];
#pragma unroll
            for (int msk = 8; msk >= 1; msk >>= 1) {
                float ov = __shfl_xor(v, msk, 64);
                int   oi = __shfl_xor(ix, msk, 64);
                if (ov < v || (ov == v && oi < ix)) { v = ov; ix = oi; }
            }
            if (m == 0) {
                int n = n0 + st * 16 + quad * 4 + i;
                uint u  = __float_as_uint(v);
                uint mm = (u & 0x80000000u) ? ~u : (u | 0x80000000u);
                u64 packed = ((u64)mm << 32) | (uint)ix;
                atomicMin(&pack[n], packed);
            }
        }
    }
}

// --------------------------------------------------------------------------
// Kernel 4: unpack merged argmin; emit index + histogram.
__global__ __launch_bounds__(256) void merge_kernel(
    const u64* __restrict__ pack,
    float* __restrict__ out_idx_f, int* __restrict__ counts)
{
    int n = blockIdx.x * 256 + threadIdx.x;
    int ix = (int)(pack[n] & 0xFFFFFFFFull);
    ix = min(max(ix, 0), KK - 1);   // safety: bug -> wrong answer, not fault
    out_idx_f[n] = (float)ix;
    atomicAdd(&counts[ix], 1);
}

// --------------------------------------------------------------------------
// Kernel 5: gather quantized values + MSE reduction. No global atomics
// (R3 post-mortem: same-address float atomics = 420 us @ VALUBusy 1%).
__global__ __launch_bounds__(256) void quant_loss_kernel(
    const float* __restrict__ x,
    const float* __restrict__ emb,
    const float* __restrict__ idxf,
    float* __restrict__ outq,
    float* __restrict__ bpart)
{
    __shared__ float red[4];
    size_t o4 = ((size_t)blockIdx.x * 256 + threadIdx.x) * 4;
    int b  = (int)(o4 >> 18);
    int d  = (int)((o4 >> 10) & 255);
    int n  = b * HW + (int)(o4 & 1023);
    int i0 = (int)idxf[n + 0];
    int i1 = (int)idxf[n + 1];
    int i2 = (int)idxf[n + 2];
    int i3 = (int)idxf[n + 3];
    i0 = min(max(i0, 0), KK - 1); i1 = min(max(i1, 0), KK - 1);
    i2 = min(max(i2, 0), KK - 1); i3 = min(max(i3, 0), KK - 1);
    const float* er = emb + (size_t)d * KK;
    float4 q;
    q.x = er[i0]; q.y = er[i1]; q.z = er[i2]; q.w = er[i3];
    const float4 xv = *(const float4*)(x + o4);
    *(float4*)(outq + o4) = q;
    float ax = q.x - xv.x, ay = q.y - xv.y, az = q.z - xv.z, aw = q.w - xv.w;
    float s = ax * ax + ay * ay + az * az + aw * aw;
#pragma unroll
    for (int off = 32; off > 0; off >>= 1) s += __shfl_down(s, off, 64);
    if ((threadIdx.x & 63) == 0) red[threadIdx.x >> 6] = s;
    __syncthreads();
    if (threadIdx.x == 0)
        bpart[blockIdx.x] = red[0] + red[1] + red[2] + red[3];
}

// --------------------------------------------------------------------------
// Kernel 6: perplexity from histogram + loss from block partials.
__global__ __launch_bounds__(256) void finalize_kernel(
    const int* __restrict__ counts,
    const float* __restrict__ bpart,
    float* __restrict__ out)
{
    __shared__ float redp[4], redl[4];
    int tid = threadIdx.x;
    float s = 0.f;
    for (int k = tid; k < KK; k += 256) {
        float p = (float)counts[k] * (1.0f / (float)NN);
        s += p * logf(p + 1e-10f);
    }
    float ls = 0.f;
    for (int k = tid; k < NBLK_QL; k += 256) ls += bpart[k];
#pragma unroll
    for (int off = 32; off > 0; off >>= 1) {
        s  += __shfl_down(s, off, 64);
        ls += __shfl_down(ls, off, 64);
    }
    if ((tid & 63) == 0) { redp[tid >> 6] = s; redl[tid >> 6] = ls; }
    __syncthreads();
    if (tid == 0) {
        float tot = redp[0] + redp[1] + redp[2] + redp[3];
        float lsum = redl[0] + redl[1] + redl[2] + redl[3];
        out[OUT_PPL]  = expf(-tot);
        out[OUT_LOSS] = lsum * 1.25f / (float)NUMEL;
    }
}

// --------------------------------------------------------------------------
extern "C" void kernel_launch(void* const* d_in, const int* in_sizes, int n_in,
                              void* d_out, int out_size, void* d_ws, size_t ws_size,
                              hipStream_t stream) {
    const float* x   = (const float*)d_in[0];
    const float* emb = (const float*)d_in[1];
    float* out = (float*)d_out;
    char*  ws  = (char*)d_ws;

    float*  h2     = (float*)(ws + WS_H2);
    int*    counts = (int*)(ws + WS_COUNTS);
    ushort* ebf    = (ushort*)(ws + WS_EBF);
    u64*    pack   = (u64*)(ws + WS_PACK);
    float*  bpart  = (float*)(ws + WS_BPART);   // aliases pack (dead after merge)

    e2h_kernel<<<KK / 256, 256, 0, stream>>>(emb, h2, counts, pack);
    prep_emb<<<256, 256, 0, stream>>>(emb, ebf);
    argmin_mfma<<<1024, 256, 0, stream>>>(x, ebf, h2, pack);
    merge_kernel<<<NN / 256, 256, 0, stream>>>(pack, out + OUT_IDX, counts);
    quant_loss_kernel<<<NBLK_QL, 256, 0, stream>>>(x, emb, out + OUT_IDX, out, bpart);
    finalize_kernel<<<1, 256, 0, stream>>>(counts, bpart, out);
}

// Round 7
// 283.331 us; speedup vs baseline: 1.8610x; 1.8610x over previous
//
#include <hip/hip_runtime.h>
#include <hip/hip_bf16.h>
#include <math.h>

typedef unsigned int  uint;
typedef unsigned short ushort;
typedef unsigned long long u64;

// Problem constants
#define DD    256      // embedding dim
#define KK    2048     // num codewords
#define HW    1024     // H*W
#define NN    32768    // rows
#define NUMEL 8388608  // total elements
#define STRIDEB (DD*HW)
#define NBLK_QL 2048   // quant_loss blocks (16 elems/thread)

// Workspace layout (bytes)
#define WS_H2     0         // 2048 f32: 0.5*||e_k||^2
#define WS_COUNTS 8192      // 2048 i32
#define WS_EBF    16512     // emb frag-ordered bf16 hi/lo: 2 MB
#define WS_PACK   2113664   // 32768 u64 packed (mapped_score<<32 | idx)
#define WS_BPART  2375808   // 2048 f32 loss partials (pack is READ by quant_loss
                            // now, so bpart must NOT alias it — R6 note)

// Output layout (floats): quantized_st | loss | perplexity | indices(as float)
#define OUT_LOSS  8388608
#define OUT_PPL   8388609
#define OUT_IDX   8388610

typedef __attribute__((ext_vector_type(8))) short  short8;   // 8 bf16 (4 VGPR)
typedef __attribute__((ext_vector_type(4))) float  float4v;  // 4 fp32 acc

__device__ __forceinline__ ushort f2bf(float f) {   // RNE fp32->bf16 bits
    uint u = __float_as_uint(f);
    return (ushort)((u + 0x7FFFu + ((u >> 16) & 1u)) >> 16);
}

// --------------------------------------------------------------------------
// Kernel 1: h2[k] = 0.5*sum_d emb[d][k]^2; zero histogram; init pack to MAX.
__global__ __launch_bounds__(256) void e2h_kernel(const float* __restrict__ emb,
                                                  float* __restrict__ h2,
                                                  int*   __restrict__ counts,
                                                  u64*   __restrict__ pack) {
    int k = blockIdx.x * 256 + threadIdx.x;
    float s = 0.f;
    for (int d = 0; d < DD; ++d) {
        float v = emb[(size_t)d * KK + k];
        s += v * v;
    }
    h2[k] = 0.5f * s;
    counts[k] = 0;
#pragma unroll
    for (int i = 0; i < 16; ++i) pack[k * 16 + i] = ~0ull;
}

// --------------------------------------------------------------------------
// Kernel 2: reorder emb (D,K) fp32 into MFMA-B-fragment-major bf16 hi/lo.
__global__ __launch_bounds__(256) void prep_emb(const float* __restrict__ emb,
                                                ushort* __restrict__ ebf) {
    int g  = blockIdx.x * 256 + threadIdx.x;
    int k  = g & (KK - 1);
    int dg = g >> 11;          // 0..31
    int d0 = dg * 8;
    int s    = dg >> 2;
    int quad = dg & 3;
    int ct   = k >> 4;
    int l    = quad * 16 + (k & 15);

    union { ushort us[8]; uint4 v; } hu, lu;
#pragma unroll
    for (int j = 0; j < 8; ++j) {
        float v = emb[(size_t)(d0 + j) * KK + k];
        ushort hb = f2bf(v);
        float  hf = __uint_as_float(((uint)hb) << 16);
        hu.us[j] = hb;
        lu.us[j] = f2bf(v - hf);
    }
    size_t hi_off = (size_t)(((ct * 8 + s) * 2 + 0) * 64 + l) * 8;
    size_t lo_off = (size_t)(((ct * 8 + s) * 2 + 1) * 64 + l) * 8;
    *(uint4*)(ebf + hi_off) = hu.v;
    *(uint4*)(ebf + lo_off) = lu.v;
}

// --------------------------------------------------------------------------
// Kernel 3: split-bf16 MFMA distance + per-row argmin over a 1024-col half.
// R7 restructure: NO LDS staging, NO K-loop barriers. B fragments are read
// straight from L2-resident ebf into registers (2-slice register double
// buffer), so each wave is an independent MFMA<->buffer_load pipeline with
// compiler-scheduled vmcnt(N) waits — the phase-lockstep that pinned
// MfmaUtil at 36% (R4/R5: serialized LDS 98k + MFMA 119k cyc/CU) is gone.
// R6 lesson: honest register budget — launch_bounds(256,2), ~220 VGPRs.
__global__ __launch_bounds__(256, 2) void argmin_mfma(
    const float*  __restrict__ x,
    const ushort* __restrict__ ebf,
    const float*  __restrict__ h2,
    u64*  __restrict__ pack)
{
    __shared__ float sH[1024];    // 4 KB: h2 slice for this col-half

    const int tid  = threadIdx.x;
    const int w    = tid >> 6;
    const int lane = tid & 63;
    const int m    = lane & 15;
    const int quad = lane >> 4;

    const int rb = blockIdx.x >> 1;
    const int ch = blockIdx.x & 1;
    const int n0 = rb * 128 + w * 32;          // wave's first row
    const int b  = n0 >> 10;
    const int hwb = n0 & 1023;
    const float* xb = x + (size_t)b * STRIDEB;
    const int cbase = ch * 1024;
    const int ctg0  = cbase >> 4;

    // h2 slice -> LDS (1024 f32 = 256 lanes x 16 B); single barrier below.
    ((float4*)sH)[tid] = ((const float4*)(h2 + cbase))[tid];

    // A fragments in registers: 2 strips x 8 slices x (hi,lo) = 128 VGPRs.
    short8 xh[2][8], xl[2][8];
#pragma unroll
    for (int st = 0; st < 2; ++st) {
        const int hw = hwb + st * 16 + m;
#pragma unroll
        for (int s = 0; s < 8; ++s) {
            const float* p = xb + (size_t)(s * 32 + quad * 8) * HW + hw;
            short8 hh, ll;
#pragma unroll
            for (int j = 0; j < 8; ++j) {
                float v = p[(size_t)j * HW];
                v = fminf(fmaxf(v, -10.f), 10.f);
                ushort hb = f2bf(v);
                float  hf = __uint_as_float(((uint)hb) << 16);
                hh[j] = (short)hb;
                ll[j] = (short)f2bf(v - hf);
            }
            xh[st][s] = hh;
            xl[st][s] = ll;
        }
    }
    __syncthreads();   // sH ready; the ONLY barrier in this kernel

    float bv[2][4] = {{1e30f,1e30f,1e30f,1e30f},{1e30f,1e30f,1e30f,1e30f}};
    int   bi[2][4] = {{0,0,0,0},{0,0,0,0}};

    // B frags as short8 array: tile ctg occupies 1024 short8; slice s hi at
    // ctg*1024 + 128*s + lane, lo at +64.
    const short8* gB = (const short8*)ebf;

    // Register double buffer: 2 slices (EH/EL [buf][slice-in-pair]).
    short8 EH[2][2], EL[2][2];
    {
        const size_t t0 = (size_t)ctg0 * 1024;
        EH[0][0] = gB[t0 + lane];        EL[0][0] = gB[t0 + 64 + lane];
        EH[0][1] = gB[t0 + 128 + lane];  EL[0][1] = gB[t0 + 192 + lane];
    }

    for (int ct = 0; ct < 64; ++ct) {
        const size_t base  = (size_t)(ctg0 + ct) * 1024;
        const size_t base2 = (ct < 63) ? base + 1024 : base;  // clamp: last re-reads own tile (cached, unused)
        float4v ahh0 = {0,0,0,0}, ahl0 = {0,0,0,0}, alh0 = {0,0,0,0};
        float4v ahh1 = {0,0,0,0}, ahl1 = {0,0,0,0}, alh1 = {0,0,0,0};
#pragma unroll
        for (int j = 0; j < 4; ++j) {
            const int cur = j & 1, nxt = cur ^ 1;
            // Prefetch slice pair (2j+2, 2j+3); wraps to next tile's (0,1).
            const size_t nb = (j < 3) ? base + (size_t)(2 * j + 2) * 128 : base2;
            EH[nxt][0] = gB[nb + lane];        EL[nxt][0] = gB[nb + 64 + lane];
            EH[nxt][1] = gB[nb + 128 + lane];  EL[nxt][1] = gB[nb + 192 + lane];
            // 12 MFMAs on the current pair (slices 2j, 2j+1).
            const int sa = 2 * j, sb = 2 * j + 1;
            alh0 = __builtin_amdgcn_mfma_f32_16x16x32_bf16(xl[0][sa], EH[cur][0], alh0, 0, 0, 0);
            ahh0 = __builtin_amdgcn_mfma_f32_16x16x32_bf16(xh[0][sa], EH[cur][0], ahh0, 0, 0, 0);
            ahl0 = __builtin_amdgcn_mfma_f32_16x16x32_bf16(xh[0][sa], EL[cur][0], ahl0, 0, 0, 0);
            alh1 = __builtin_amdgcn_mfma_f32_16x16x32_bf16(xl[1][sa], EH[cur][0], alh1, 0, 0, 0);
            ahh1 = __builtin_amdgcn_mfma_f32_16x16x32_bf16(xh[1][sa], EH[cur][0], ahh1, 0, 0, 0);
            ahl1 = __builtin_amdgcn_mfma_f32_16x16x32_bf16(xh[1][sa], EL[cur][0], ahl1, 0, 0, 0);
            alh0 = __builtin_amdgcn_mfma_f32_16x16x32_bf16(xl[0][sb], EH[cur][1], alh0, 0, 0, 0);
            ahh0 = __builtin_amdgcn_mfma_f32_16x16x32_bf16(xh[0][sb], EH[cur][1], ahh0, 0, 0, 0);
            ahl0 = __builtin_amdgcn_mfma_f32_16x16x32_bf16(xh[0][sb], EL[cur][1], ahl0, 0, 0, 0);
            alh1 = __builtin_amdgcn_mfma_f32_16x16x32_bf16(xl[1][sb], EH[cur][1], alh1, 0, 0, 0);
            ahh1 = __builtin_amdgcn_mfma_f32_16x16x32_bf16(xh[1][sb], EH[cur][1], ahh1, 0, 0, 0);
            ahl1 = __builtin_amdgcn_mfma_f32_16x16x32_bf16(xh[1][sb], EL[cur][1], ahl1, 0, 0, 0);
        }
        const int c  = cbase + ct * 16 + m;
        const float hv = sH[ct * 16 + m];
#pragma unroll
        for (int i = 0; i < 4; ++i) {
            float s0 = hv - (ahh0[i] + (ahl0[i] + alh0[i]));
            float s1 = hv - (ahh1[i] + (ahl1[i] + alh1[i]));
            if (s0 < bv[0][i]) { bv[0][i] = s0; bi[0][i] = c; }
            if (s1 < bv[1][i]) { bv[1][i] = s1; bi[1][i] = c; }
        }
    }

    // Reduce across the 16 lanes of each quad, then atomicMin-merge.
    // Packed (monotone(score)<<32 | idx): lexicographic min == min-value,
    // then min-index — jnp.argmin tie order. Verified R6.
#pragma unroll
    for (int st = 0; st < 2; ++st) {
#pragma unroll
        for (int i = 0; i < 4; ++i) {
            float v  = bv[st][i];
            int   ix = bi[st][i];
#pragma unroll
            for (int msk = 8; msk >= 1; msk >>= 1) {
                float ov = __shfl_xor(v, msk, 64);
                int   oi = __shfl_xor(ix, msk, 64);
                if (ov < v || (ov == v && oi < ix)) { v = ov; ix = oi; }
            }
            if (m == 0) {
                int n = n0 + st * 16 + quad * 4 + i;
                uint u  = __float_as_uint(v);
                uint mm = (u & 0x80000000u) ? ~u : (u | 0x80000000u);
                atomicMin(&pack[n], ((u64)mm << 32) | (uint)ix);
            }
        }
    }
}

// --------------------------------------------------------------------------
// Kernel 4: gather quantized values + MSE reduction + (fused) index emit +
// histogram. 16 elems/thread for gather ILP. Reads pack directly (merge
// kernel eliminated). d==0 threads write out_idx_f and the histogram.
// No same-address float atomics (R3 lesson).
__global__ __launch_bounds__(256) void quant_loss_kernel(
    const float* __restrict__ x,
    const float* __restrict__ emb,
    const u64*   __restrict__ pack,
    float* __restrict__ outq,
    float* __restrict__ out_idx_f,
    int*   __restrict__ counts,
    float* __restrict__ bpart)
{
    __shared__ float red[4];
    const size_t o = ((size_t)blockIdx.x * 256 + threadIdx.x) * 16;
    const int b  = (int)(o >> 18);
    const int d  = (int)((o >> 10) & 255);
    const int n  = b * HW + (int)(o & 1023);
    const float* er = emb + (size_t)d * KK;

    float s = 0.f;
#pragma unroll
    for (int u = 0; u < 4; ++u) {
        const int nn = n + u * 4;
        int iv[4];
#pragma unroll
        for (int v = 0; v < 4; ++v) {
            int ix = (int)(pack[nn + v] & 0xFFFFFFFFull);
            iv[v] = min(max(ix, 0), KK - 1);  // safety: bug -> wrong answer
        }
        float4 q;
        q.x = er[iv[0]]; q.y = er[iv[1]]; q.z = er[iv[2]]; q.w = er[iv[3]];
        const float4 xv = *(const float4*)(x + o + u * 4);
        *(float4*)(outq + o + u * 4) = q;
        float ax = q.x - xv.x, ay = q.y - xv.y, az = q.z - xv.z, aw = q.w - xv.w;
        s += ax * ax + ay * ay + az * az + aw * aw;
        if (d == 0) {
#pragma unroll
            for (int v = 0; v < 4; ++v) {
                out_idx_f[nn + v] = (float)iv[v];
                atomicAdd(&counts[iv[v]], 1);
            }
        }
    }
#pragma unroll
    for (int off = 32; off > 0; off >>= 1) s += __shfl_down(s, off, 64);
    if ((threadIdx.x & 63) == 0) red[threadIdx.x >> 6] = s;
    __syncthreads();
    if (threadIdx.x == 0)
        bpart[blockIdx.x] = red[0] + red[1] + red[2] + red[3];
}

// --------------------------------------------------------------------------
// Kernel 5: perplexity from histogram + loss from block partials.
__global__ __launch_bounds__(256) void finalize_kernel(
    const int* __restrict__ counts,
    const float* __restrict__ bpart,
    float* __restrict__ out)
{
    __shared__ float redp[4], redl[4];
    int tid = threadIdx.x;
    float s = 0.f;
    for (int k = tid; k < KK; k += 256) {
        float p = (float)counts[k] * (1.0f / (float)NN);
        s += p * logf(p + 1e-10f);
    }
    float ls = 0.f;
    for (int k = tid; k < NBLK_QL; k += 256) ls += bpart[k];
#pragma unroll
    for (int off = 32; off > 0; off >>= 1) {
        s  += __shfl_down(s, off, 64);
        ls += __shfl_down(ls, off, 64);
    }
    if ((tid & 63) == 0) { redp[tid >> 6] = s; redl[tid >> 6] = ls; }
    __syncthreads();
    if (tid == 0) {
        float tot = redp[0] + redp[1] + redp[2] + redp[3];
        float lsum = redl[0] + redl[1] + redl[2] + redl[3];
        out[OUT_PPL]  = expf(-tot);
        out[OUT_LOSS] = lsum * 1.25f / (float)NUMEL;
    }
}

// --------------------------------------------------------------------------
extern "C" void kernel_launch(void* const* d_in, const int* in_sizes, int n_in,
                              void* d_out, int out_size, void* d_ws, size_t ws_size,
                              hipStream_t stream) {
    const float* x   = (const float*)d_in[0];
    const float* emb = (const float*)d_in[1];
    float* out = (float*)d_out;
    char*  ws  = (char*)d_ws;

    float*  h2     = (float*)(ws + WS_H2);
    int*    counts = (int*)(ws + WS_COUNTS);
    ushort* ebf    = (ushort*)(ws + WS_EBF);
    u64*    pack   = (u64*)(ws + WS_PACK);
    float*  bpart  = (float*)(ws + WS_BPART);

    e2h_kernel<<<KK / 256, 256, 0, stream>>>(emb, h2, counts, pack);
    prep_emb<<<256, 256, 0, stream>>>(emb, ebf);
    argmin_mfma<<<512, 256, 0, stream>>>(x, ebf, h2, pack);
    quant_loss_kernel<<<NBLK_QL, 256, 0, stream>>>(x, emb, pack, out,
                                                   out + OUT_IDX, counts, bpart);
    finalize_kernel<<<1, 256, 0, stream>>>(counts, bpart, out);
}

// Round 8
// 262.508 us; speedup vs baseline: 2.0086x; 1.0793x over previous
//
#include <hip/hip_runtime.h>
#include <hip/hip_bf16.h>
#include <math.h>

typedef unsigned int  uint;
typedef unsigned short ushort;
typedef unsigned long long u64;

// Problem constants
#define DD    256      // embedding dim
#define KK    2048     // num codewords
#define HW    1024     // H*W
#define NN    32768    // rows
#define NUMEL 8388608  // total elements
#define STRIDEB (DD*HW)
#define NBLK_QL 2048   // quant_loss blocks (16 elems/thread)

// Workspace layout (bytes)
#define WS_H2     0         // 2048 f32: 0.5*||e_k||^2
#define WS_COUNTS 8192      // 2048 i32
#define WS_EBF    16512     // emb frag-ordered bf16 hi/lo: 2 MB
#define WS_PACK   2113664   // 32768 u64 packed (mapped_score<<32 | idx)
#define WS_BPART  2375808   // 2048 f32 loss partials (must NOT alias pack)

// Output layout (floats): quantized_st | loss | perplexity | indices(as float)
#define OUT_LOSS  8388608
#define OUT_PPL   8388609
#define OUT_IDX   8388610

typedef __attribute__((ext_vector_type(8))) short  short8;   // 8 bf16 (4 VGPR)
typedef __attribute__((ext_vector_type(4))) float  float4v;  // 4 fp32 acc

__device__ __forceinline__ ushort f2bf(float f) {   // RNE fp32->bf16 bits
    uint u = __float_as_uint(f);
    return (ushort)((u + 0x7FFFu + ((u >> 16) & 1u)) >> 16);
}

// --------------------------------------------------------------------------
// Kernel 1: h2[k] = 0.5*sum_d emb[d][k]^2; zero histogram; init pack to MAX.
__global__ __launch_bounds__(256) void e2h_kernel(const float* __restrict__ emb,
                                                  float* __restrict__ h2,
                                                  int*   __restrict__ counts,
                                                  u64*   __restrict__ pack) {
    int k = blockIdx.x * 256 + threadIdx.x;
    float s = 0.f;
    for (int d = 0; d < DD; ++d) {
        float v = emb[(size_t)d * KK + k];
        s += v * v;
    }
    h2[k] = 0.5f * s;
    counts[k] = 0;
#pragma unroll
    for (int i = 0; i < 16; ++i) pack[k * 16 + i] = ~0ull;
}

// --------------------------------------------------------------------------
// Kernel 2: reorder emb (D,K) fp32 into MFMA-B-fragment-major bf16 hi/lo.
__global__ __launch_bounds__(256) void prep_emb(const float* __restrict__ emb,
                                                ushort* __restrict__ ebf) {
    int g  = blockIdx.x * 256 + threadIdx.x;
    int k  = g & (KK - 1);
    int dg = g >> 11;          // 0..31
    int d0 = dg * 8;
    int s    = dg >> 2;
    int quad = dg & 3;
    int ct   = k >> 4;
    int l    = quad * 16 + (k & 15);

    union { ushort us[8]; uint4 v; } hu, lu;
#pragma unroll
    for (int j = 0; j < 8; ++j) {
        float v = emb[(size_t)(d0 + j) * KK + k];
        ushort hb = f2bf(v);
        float  hf = __uint_as_float(((uint)hb) << 16);
        hu.us[j] = hb;
        lu.us[j] = f2bf(v - hf);
    }
    size_t hi_off = (size_t)(((ct * 8 + s) * 2 + 0) * 64 + l) * 8;
    size_t lo_off = (size_t)(((ct * 8 + s) * 2 + 1) * 64 + l) * 8;
    *(uint4*)(ebf + hi_off) = hu.v;
    *(uint4*)(ebf + lo_off) = lu.v;
}

// --------------------------------------------------------------------------
// Kernel 3: PRODUCER-CONSUMER wave-specialized MFMA argmin.
// Block = 320 threads = 5 waves. Wave 4 = producer: stages 16 KB B tiles
// into a 4-slot LDS ring (global_load_lds 16B) and publishes LDS tokens.
// Waves 0-3 = consumers: spin on token (broadcast ds_read), then
// ds_read B frags + 48 MFMA + argmin. NO __syncthreads in the K-loop, so
// consumer waves drift out of phase and MFMA/VALU/LDS pipes overlap across
// waves (m114). R4-R7 post-mortems: any barriered/lockstep structure pins
// MfmaUtil at <=36% because the phases serialize.
__global__ __launch_bounds__(320, 2) void argmin_mfma(
    const float*  __restrict__ x,
    const ushort* __restrict__ ebf,
    const float*  __restrict__ h2,
    u64*  __restrict__ pack)
{
    __shared__ ushort sB[4 * 8192];   // 64 KB: 4-slot ring of 16 KB B tiles
    __shared__ float  sH[1024];       // 4 KB: h2 slice for this col-half
    __shared__ int    ready[4];       // token: tile t staged in slot t&3
    __shared__ int    done[4];        // consumers finished with slot

    const int tid  = threadIdx.x;
    const int w    = tid >> 6;
    const int lane = tid & 63;

    const int rb = blockIdx.x >> 1;
    const int ch = blockIdx.x & 1;
    const int cbase = ch * 1024;
    const int ctg0  = cbase >> 4;

    if (tid < 4) { ready[tid] = 0; done[tid] = 4; }   // slots start "free"
    if (tid < 256) ((float4*)sH)[tid] = ((const float4*)(h2 + cbase))[tid];
    __syncthreads();   // the ONLY block-wide barrier

    volatile int* vready = (volatile int*)ready;
    volatile int* vdone  = (volatile int*)done;

    if (w == 4) {
        // ---------------- producer wave ----------------
        for (int t = 0; t < 64; ++t) {
            const int slot = t & 3;
            while (vdone[slot] != 4) __builtin_amdgcn_s_sleep(1);
            if (lane == 0) vdone[slot] = 0;
            const char* gb = (const char*)ebf + (size_t)(ctg0 + t) * 16384;
            char* lb = (char*)sB + (slot << 14);
#pragma unroll
            for (int i = 0; i < 16; ++i) {
                __builtin_amdgcn_global_load_lds(
                    (const __attribute__((address_space(1))) uint*)(gb + (i << 10) + lane * 16),
                    (__attribute__((address_space(3))) uint*)(lb + (i << 10)),
                    16, 0, 0);
            }
            __builtin_amdgcn_s_waitcnt(0);   // DMA landed in LDS
            __threadfence_block();
            if (lane == 0) vready[slot] = t + 1;
        }
        return;
    }

    // ---------------- consumer waves (0..3) ----------------
    const int m    = lane & 15;
    const int quad = lane >> 4;
    const int n0 = rb * 128 + w * 32;          // wave's first row
    const int b  = n0 >> 10;
    const int hwb = n0 & 1023;
    const float* xb = x + (size_t)b * STRIDEB;

    // A fragments in registers: 2 strips x 8 slices x (hi,lo) = 128 VGPRs.
    // (Producer overlaps tile 0..3 staging with this ~2k-cycle prologue.)
    short8 xh[2][8], xl[2][8];
#pragma unroll
    for (int st = 0; st < 2; ++st) {
        const int hw = hwb + st * 16 + m;
#pragma unroll
        for (int s = 0; s < 8; ++s) {
            const float* p = xb + (size_t)(s * 32 + quad * 8) * HW + hw;
            short8 hh, ll;
#pragma unroll
            for (int j = 0; j < 8; ++j) {
                float v = p[(size_t)j * HW];
                v = fminf(fmaxf(v, -10.f), 10.f);
                ushort hb = f2bf(v);
                float  hf = __uint_as_float(((uint)hb) << 16);
                hh[j] = (short)hb;
                ll[j] = (short)f2bf(v - hf);
            }
            xh[st][s] = hh;
            xl[st][s] = ll;
        }
    }

    float bv[2][4] = {{1e30f,1e30f,1e30f,1e30f},{1e30f,1e30f,1e30f,1e30f}};
    int   bi[2][4] = {{0,0,0,0},{0,0,0,0}};

    for (int ct = 0; ct < 64; ++ct) {
        const int slot = ct & 3;
        while (vready[slot] != ct + 1) __builtin_amdgcn_s_sleep(1);
        __threadfence_block();

        const ushort* bufc = sB + (slot << 13);
        // Chained accumulator: acomb collects xh*el + xl*eh (epilogue 3->2 ops,
        // acc regs 24->16).
        float4v ahh0 = {0,0,0,0}, ac0 = {0,0,0,0};
        float4v ahh1 = {0,0,0,0}, ac1 = {0,0,0,0};
#pragma unroll
        for (int s = 0; s < 8; ++s) {
            short8 eh = *(const short8*)&bufc[(s * 2 + 0) * 512 + lane * 8];
            short8 el = *(const short8*)&bufc[(s * 2 + 1) * 512 + lane * 8];
            ahh0 = __builtin_amdgcn_mfma_f32_16x16x32_bf16(xh[0][s], eh, ahh0, 0, 0, 0);
            ac0  = __builtin_amdgcn_mfma_f32_16x16x32_bf16(xh[0][s], el, ac0, 0, 0, 0);
            ac0  = __builtin_amdgcn_mfma_f32_16x16x32_bf16(xl[0][s], eh, ac0, 0, 0, 0);
            ahh1 = __builtin_amdgcn_mfma_f32_16x16x32_bf16(xh[1][s], eh, ahh1, 0, 0, 0);
            ac1  = __builtin_amdgcn_mfma_f32_16x16x32_bf16(xh[1][s], el, ac1, 0, 0, 0);
            ac1  = __builtin_amdgcn_mfma_f32_16x16x32_bf16(xl[1][s], eh, ac1, 0, 0, 0);
        }
        __threadfence_block();               // ds reads drained before release
        if (lane == 0) atomicAdd((int*)&done[slot], 1);

        const int c  = cbase + ct * 16 + m;
        const float hv = sH[ct * 16 + m];
#pragma unroll
        for (int i = 0; i < 4; ++i) {
            float s0 = (hv - ahh0[i]) - ac0[i];
            float s1 = (hv - ahh1[i]) - ac1[i];
            if (s0 < bv[0][i]) { bv[0][i] = s0; bi[0][i] = c; }
            if (s1 < bv[1][i]) { bv[1][i] = s1; bi[1][i] = c; }
        }
    }

    // Reduce across the 16 lanes of each quad, then atomicMin-merge.
    // Packed (monotone(score)<<32 | idx): lexicographic min == min-value,
    // then min-index — jnp.argmin tie order. Verified R6/R7.
#pragma unroll
    for (int st = 0; st < 2; ++st) {
#pragma unroll
        for (int i = 0; i < 4; ++i) {
            float v  = bv[st][i];
            int   ix = bi[st][i];
#pragma unroll
            for (int msk = 8; msk >= 1; msk >>= 1) {
                float ov = __shfl_xor(v, msk, 64);
                int   oi = __shfl_xor(ix, msk, 64);
                if (ov < v || (ov == v && oi < ix)) { v = ov; ix = oi; }
            }
            if (m == 0) {
                int n = n0 + st * 16 + quad * 4 + i;
                uint u  = __float_as_uint(v);
                uint mm = (u & 0x80000000u) ? ~u : (u | 0x80000000u);
                atomicMin(&pack[n], ((u64)mm << 32) | (uint)ix);
            }
        }
    }
}

// --------------------------------------------------------------------------
// Kernel 4: gather quantized values + MSE reduction + fused index emit +
// histogram. Reads pack directly. No same-address float atomics (R3 lesson).
__global__ __launch_bounds__(256) void quant_loss_kernel(
    const float* __restrict__ x,
    const float* __restrict__ emb,
    const u64*   __restrict__ pack,
    float* __restrict__ outq,
    float* __restrict__ out_idx_f,
    int*   __restrict__ counts,
    float* __restrict__ bpart)
{
    __shared__ float red[4];
    const size_t o = ((size_t)blockIdx.x * 256 + threadIdx.x) * 16;
    const int b  = (int)(o >> 18);
    const int d  = (int)((o >> 10) & 255);
    const int n  = b * HW + (int)(o & 1023);
    const float* er = emb + (size_t)d * KK;

    float s = 0.f;
#pragma unroll
    for (int u = 0; u < 4; ++u) {
        const int nn = n + u * 4;
        int iv[4];
#pragma unroll
        for (int v = 0; v < 4; ++v) {
            int ix = (int)(pack[nn + v] & 0xFFFFFFFFull);
            iv[v] = min(max(ix, 0), KK - 1);  // safety: bug -> wrong answer
        }
        float4 q;
        q.x = er[iv[0]]; q.y = er[iv[1]]; q.z = er[iv[2]]; q.w = er[iv[3]];
        const float4 xv = *(const float4*)(x + o + u * 4);
        *(float4*)(outq + o + u * 4) = q;
        float ax = q.x - xv.x, ay = q.y - xv.y, az = q.z - xv.z, aw = q.w - xv.w;
        s += ax * ax + ay * ay + az * az + aw * aw;
        if (d == 0) {
#pragma unroll
            for (int v = 0; v < 4; ++v) {
                out_idx_f[nn + v] = (float)iv[v];
                atomicAdd(&counts[iv[v]], 1);
            }
        }
    }
#pragma unroll
    for (int off = 32; off > 0; off >>= 1) s += __shfl_down(s, off, 64);
    if ((threadIdx.x & 63) == 0) red[threadIdx.x >> 6] = s;
    __syncthreads();
    if (threadIdx.x == 0)
        bpart[blockIdx.x] = red[0] + red[1] + red[2] + red[3];
}

// --------------------------------------------------------------------------
// Kernel 5: perplexity from histogram + loss from block partials.
__global__ __launch_bounds__(256) void finalize_kernel(
    const int* __restrict__ counts,
    const float* __restrict__ bpart,
    float* __restrict__ out)
{
    __shared__ float redp[4], redl[4];
    int tid = threadIdx.x;
    float s = 0.f;
    for (int k = tid; k < KK; k += 256) {
        float p = (float)counts[k] * (1.0f / (float)NN);
        s += p * logf(p + 1e-10f);
    }
    float ls = 0.f;
    for (int k = tid; k < NBLK_QL; k += 256) ls += bpart[k];
#pragma unroll
    for (int off = 32; off > 0; off >>= 1) {
        s  += __shfl_down(s, off, 64);
        ls += __shfl_down(ls, off, 64);
    }
    if ((tid & 63) == 0) { redp[tid >> 6] = s; redl[tid >> 6] = ls; }
    __syncthreads();
    if (tid == 0) {
        float tot = redp[0] + redp[1] + redp[2] + redp[3];
        float lsum = redl[0] + redl[1] + redl[2] + redl[3];
        out[OUT_PPL]  = expf(-tot);
        out[OUT_LOSS] = lsum * 1.25f / (float)NUMEL;
    }
}

// --------------------------------------------------------------------------
extern "C" void kernel_launch(void* const* d_in, const int* in_sizes, int n_in,
                              void* d_out, int out_size, void* d_ws, size_t ws_size,
                              hipStream_t stream) {
    const float* x   = (const float*)d_in[0];
    const float* emb = (const float*)d_in[1];
    float* out = (float*)d_out;
    char*  ws  = (char*)d_ws;

    float*  h2     = (float*)(ws + WS_H2);
    int*    counts = (int*)(ws + WS_COUNTS);
    ushort* ebf    = (ushort*)(ws + WS_EBF);
    u64*    pack   = (u64*)(ws + WS_PACK);
    float*  bpart  = (float*)(ws + WS_BPART);

    e2h_kernel<<<KK / 256, 256, 0, stream>>>(emb, h2, counts, pack);
    prep_emb<<<256, 256, 0, stream>>>(emb, ebf);
    argmin_mfma<<<512, 320, 0, stream>>>(x, ebf, h2, pack);
    quant_loss_kernel<<<NBLK_QL, 256, 0, stream>>>(x, emb, pack, out,
                                                   out + OUT_IDX, counts, bpart);
    finalize_kernel<<<1, 256, 0, stream>>>(counts, bpart, out);
}